// Round 6
// baseline (852.614 us; speedup 1.0000x reference)
//
#include <hip/hip_runtime.h>
#include <cstdint>
#include <cstddef>

#define N_NODES 100000
#define N_EDGES 3200000
#define DD 256
#define KK 512            // concatenated K: [emb+nb | nb*emb]
#define MPAD 100096       // 3128 * 32
#define NSCAN 98          // ceil(N_NODES / 1024)
#define NGRP 8            // row-groups (== XCDs, heuristic)
#define GRP_ROWS 12500    // N_NODES / NGRP
#define NSLOT 256         // edge slots
#define SLOT_E 12500      // N_EDGES / NSLOT

typedef __attribute__((ext_vector_type(8))) __bf16 bf16x8;
typedef __attribute__((ext_vector_type(4))) __bf16 bf16x4;
typedef __attribute__((ext_vector_type(4))) float f32x4;

// ---------------- converts ----------------

__global__ void conve_kernel(const float* __restrict__ emb, __bf16* __restrict__ embB) {
  int i = blockIdx.x * blockDim.x + threadIdx.x;   // quad index, N*64 total
  float4 v = ((const float4*)emb)[i];
  bf16x4 o;
  o[0] = (__bf16)v.x; o[1] = (__bf16)v.y; o[2] = (__bf16)v.z; o[3] = (__bf16)v.w;
  ((bf16x4*)embB)[i] = o;
}

// Wt[n][k] = (k<256 ? W1[k][n] : W2[k-256][n]) as bf16, row-major [256][512]
__global__ void convw_kernel(const float* __restrict__ W1, const float* __restrict__ W2,
                             __bf16* __restrict__ Wt) {
  int idx = blockIdx.x * blockDim.x + threadIdx.x; // 0..131071 ; idx = n*512 + k
  int n = idx >> 9;
  int k = idx & 511;
  float v = (k < 256) ? W1[k * 256 + n] : W2[(k - 256) * 256 + n];
  Wt[idx] = (__bf16)v;
}

// ---------------- CSR build ----------------

__global__ void zero_ints_kernel(int* __restrict__ p, int n) {
  int i = blockIdx.x * blockDim.x + threadIdx.x;
  if (i < n) p[i] = 0;
}

// XCD-localized histogram: block b -> row-group (b&7), edge slot (b>>3).
// counts lines for group g are touched by ONE XCD -> atomics stay in local L2.
__global__ void hist_kernel(const int* __restrict__ rows, int* __restrict__ counts) {
  const int g = blockIdx.x & (NGRP - 1);
  const int s = blockIdx.x >> 3;
  const int rlo = g * GRP_ROWS;
  const int rhi = rlo + GRP_ROWS;
  const int base = s * SLOT_E;
  for (int i = base + threadIdx.x; i < base + SLOT_E; i += 256) {
    int r = rows[i];
    if (r >= rlo && r < rhi) atomicAdd(&counts[r], 1);
  }
}

__global__ void scan_block_kernel(const int* __restrict__ counts, int* __restrict__ offsets,
                                  int* __restrict__ blockSums, int n) {
  __shared__ int s[1024];
  int t = threadIdx.x;
  int i = blockIdx.x * 1024 + t;
  int v = (i < n) ? counts[i] : 0;
  s[t] = v;
  __syncthreads();
  for (int off = 1; off < 1024; off <<= 1) {
    int x = (t >= off) ? s[t - off] : 0;
    __syncthreads();
    s[t] += x;
    __syncthreads();
  }
  if (i < n) offsets[i + 1] = s[t];       // block-local inclusive scan (base added later)
  if (t == 1023) blockSums[blockIdx.x] = s[1023];
}

__global__ void scan_sums_kernel(const int* __restrict__ blockSums, int* __restrict__ blockBase,
                                 int nb, int* __restrict__ offsets) {
  __shared__ int s[128];
  int t = threadIdx.x;          // launched with 128 threads, nb <= 128
  int v = (t < nb) ? blockSums[t] : 0;
  s[t] = v;
  __syncthreads();
  for (int off = 1; off < 128; off <<= 1) {
    int x = (t >= off) ? s[t - off] : 0;
    __syncthreads();
    s[t] += x;
    __syncthreads();
  }
  if (t < nb) blockBase[t] = s[t] - v;    // exclusive
  if (t == 0) offsets[0] = 0;
}

__global__ void scan_add_kernel(const int* __restrict__ counts, int* __restrict__ offsets,
                                const int* __restrict__ blockBase, int* __restrict__ cursor, int n) {
  int i = blockIdx.x * 1024 + threadIdx.x;
  if (i < n) {
    int incl = offsets[i + 1] + blockBase[blockIdx.x];
    offsets[i + 1] = incl;
    cursor[i] = incl - counts[i];         // exclusive prefix = row start
  }
}

// XCD-localized packed binning (round-4 win: WRITE_SIZE 293MB -> ~1x)
__global__ void bin_kernel(const int* __restrict__ rows, const int* __restrict__ cols,
                           const float* __restrict__ vals, int* __restrict__ cursor,
                           uint2* __restrict__ sedge) {
  const int g = blockIdx.x & (NGRP - 1);
  const int s = blockIdx.x >> 3;
  const int rlo = g * GRP_ROWS;
  const int rhi = rlo + GRP_ROWS;
  const int base = s * SLOT_E;
  for (int i = base + threadIdx.x; i < base + SLOT_E; i += 256) {
    int r = rows[i];
    if (r >= rlo && r < rhi) {
      int pos = atomicAdd(&cursor[r], 1);
      sedge[pos] = make_uint2((unsigned)cols[i], __float_as_uint(vals[i]));
    }
  }
}

// ---------------- fused SpMM + GEMM ----------------
// Block owns 32 output rows. Phase 1: each of 4 waves gathers 8 rows,
// writes X-rows [emb+nb | nb*emb] bf16 into a swizzled 32KB LDS tile.
// Phase 2: wave w computes out[32 x 64] for N-cols [w*64, w*64+64),
// K=512 from LDS (A) and L2-resident Wt (B), writes fp32 out.

__global__ __launch_bounds__(256) void spmm_gemm_kernel(
    const __bf16* __restrict__ embB, const int* __restrict__ offsets,
    const uint2* __restrict__ sedge, const __bf16* __restrict__ Wt,
    float* __restrict__ out) {
  __shared__ __align__(16) char Xs[32 * 1024];    // 32 rows x 1024B, XOR-swizzled
  const int t = threadIdx.x;
  const int w = t >> 6, lane = t & 63;
  const int m0 = blockIdx.x * 32;
  const bf16x4* ev = (const bf16x4*)embB;         // ev[c*64 + lane] = emb[c][4l..4l+3]

  // ---- phase 1: gather. wave w builds local rows [w*8, w*8+8)
  for (int rr = 0; rr < 8; ++rr) {
    const int lr = (w << 3) + rr;
    const int r = m0 + lr;
    const int sw = (lr & 7) << 4;                 // T2 swizzle: byte ^= (row&7)<<4
    bf16x4* q1 = (bf16x4*)(Xs + lr * 1024 + ((lane * 8) ^ sw));
    bf16x4* q2 = (bf16x4*)(Xs + lr * 1024 + ((512 + lane * 8) ^ sw));
    if (r >= N_NODES) {                           // pad rows -> zeros
      bf16x4 z;
      z[0] = (__bf16)0.f; z[1] = (__bf16)0.f; z[2] = (__bf16)0.f; z[3] = (__bf16)0.f;
      *q1 = z; *q2 = z;
      continue;
    }
    float ax = 0.f, ay = 0.f, az = 0.f, aw = 0.f;
    int e = offsets[r];
    const int eend = offsets[r + 1];
    for (; e + 3 < eend; e += 4) {                // 4 gathers in flight
      uint2 e0 = sedge[e], e1 = sedge[e + 1], e2 = sedge[e + 2], e3 = sedge[e + 3];
      float v0 = __uint_as_float(e0.y), v1 = __uint_as_float(e1.y);
      float v2 = __uint_as_float(e2.y), v3 = __uint_as_float(e3.y);
      bf16x4 x0 = ev[(size_t)e0.x * 64 + lane];
      bf16x4 x1 = ev[(size_t)e1.x * 64 + lane];
      bf16x4 x2 = ev[(size_t)e2.x * 64 + lane];
      bf16x4 x3 = ev[(size_t)e3.x * 64 + lane];
      ax = fmaf(v0, (float)x0[0], ax); ay = fmaf(v0, (float)x0[1], ay);
      az = fmaf(v0, (float)x0[2], az); aw = fmaf(v0, (float)x0[3], aw);
      ax = fmaf(v1, (float)x1[0], ax); ay = fmaf(v1, (float)x1[1], ay);
      az = fmaf(v1, (float)x1[2], az); aw = fmaf(v1, (float)x1[3], aw);
      ax = fmaf(v2, (float)x2[0], ax); ay = fmaf(v2, (float)x2[1], ay);
      az = fmaf(v2, (float)x2[2], az); aw = fmaf(v2, (float)x2[3], aw);
      ax = fmaf(v3, (float)x3[0], ax); ay = fmaf(v3, (float)x3[1], ay);
      az = fmaf(v3, (float)x3[2], az); aw = fmaf(v3, (float)x3[3], aw);
    }
    for (; e < eend; ++e) {
      uint2 ee = sedge[e];
      float v = __uint_as_float(ee.y);
      bf16x4 x = ev[(size_t)ee.x * 64 + lane];
      ax = fmaf(v, (float)x[0], ax); ay = fmaf(v, (float)x[1], ay);
      az = fmaf(v, (float)x[2], az); aw = fmaf(v, (float)x[3], aw);
    }
    bf16x4 er = ev[(size_t)r * 64 + lane];
    float ex = (float)er[0], ey = (float)er[1], ez = (float)er[2], ew = (float)er[3];
    bf16x4 o1, o2;
    o1[0] = (__bf16)(ex + ax); o1[1] = (__bf16)(ey + ay);
    o1[2] = (__bf16)(ez + az); o1[3] = (__bf16)(ew + aw);
    o2[0] = (__bf16)(ex * ax); o2[1] = (__bf16)(ey * ay);
    o2[2] = (__bf16)(ez * az); o2[3] = (__bf16)(ew * aw);
    *q1 = o1;
    *q2 = o2;
  }
  __syncthreads();

  // ---- phase 2: GEMM. wave w -> N-cols [w*64, w*64+64), M=32, K=512
  f32x4 acc[2][4];
#pragma unroll
  for (int mt = 0; mt < 2; ++mt)
#pragma unroll
    for (int j = 0; j < 4; ++j) {
      f32x4 z = {0.f, 0.f, 0.f, 0.f};
      acc[mt][j] = z;
    }
  const int n0w = w << 6;
  const int l15 = lane & 15, lhi = lane >> 4;
#pragma unroll 4
  for (int ks = 0; ks < 16; ++ks) {
    const int kk = ks << 5;                       // K-step of 32
    bf16x8 af[2], bg[4];
#pragma unroll
    for (int mt = 0; mt < 2; ++mt) {
      const int ar = (mt << 4) + l15;             // local A row (m = lane&15)
      int off = ar * 1024 + (kk << 1) + (lhi << 4);
      off ^= (ar & 7) << 4;                       // same swizzle as write side
      af[mt] = *(const bf16x8*)(Xs + off);
    }
#pragma unroll
    for (int j = 0; j < 4; ++j)
      bg[j] = *(const bf16x8*)(Wt + (size_t)(n0w + (j << 4) + l15) * KK + kk + (lhi << 3));
#pragma unroll
    for (int mt = 0; mt < 2; ++mt)
#pragma unroll
      for (int j = 0; j < 4; ++j)
        acc[mt][j] = __builtin_amdgcn_mfma_f32_16x16x32_bf16(af[mt], bg[j], acc[mt][j], 0, 0, 0);
  }

  // epilogue: C col = lane&15 (n), row = (lane>>4)*4 + r (m)
  const int ocol0 = n0w + l15;
#pragma unroll
  for (int mt = 0; mt < 2; ++mt)
#pragma unroll
    for (int j = 0; j < 4; ++j)
#pragma unroll
      for (int r2 = 0; r2 < 4; ++r2) {
        const int row = m0 + (mt << 4) + (lhi << 2) + r2;
        if (row < N_NODES) out[(size_t)row * DD + ocol0 + (j << 4)] = acc[mt][j][r2];
      }
}

// ---------------- launch ----------------

extern "C" void kernel_launch(void* const* d_in, const int* in_sizes, int n_in,
                              void* d_out, int out_size, void* d_ws, size_t ws_size,
                              hipStream_t stream) {
  const float* emb  = (const float*)d_in[0];
  const float* ev   = (const float*)d_in[1];
  const float* W1   = (const float*)d_in[2];
  const float* W2   = (const float*)d_in[3];
  const int* erows  = (const int*)d_in[4];
  const int* ecols  = (const int*)d_in[5];
  float* out = (float*)d_out;
  char* ws = (char*)d_ws;

  // workspace layout
  const size_t OFF_EMB = 0;                                     // N*256*2 = 51,200,000
  const size_t OFF_WT  = OFF_EMB + (size_t)N_NODES * DD * 2;    // 512*256*2 = 262,144
  const size_t OFF_CNT = OFF_WT  + (size_t)KK * DD * 2;
  const size_t OFF_OFS = OFF_CNT + 401408;
  const size_t OFF_CUR = OFF_OFS + 401408;
  const size_t OFF_BS  = OFF_CUR + 401408;
  const size_t OFF_BB  = OFF_BS  + 4096;
  const size_t OFF_SE  = OFF_BB  + 4096;                        // N_EDGES*8 packed (col,val)

  __bf16* embB  = (__bf16*)(ws + OFF_EMB);
  __bf16* Wt    = (__bf16*)(ws + OFF_WT);
  int* counts   = (int*)(ws + OFF_CNT);
  int* offsets  = (int*)(ws + OFF_OFS);
  int* cursor   = (int*)(ws + OFF_CUR);
  int* bsums    = (int*)(ws + OFF_BS);
  int* bbase    = (int*)(ws + OFF_BB);
  uint2* sedge  = (uint2*)(ws + OFF_SE);

  // converts (independent)
  conve_kernel<<<(N_NODES * 64) / 256, 256, 0, stream>>>(emb, embB);
  convw_kernel<<<(KK * DD) / 256, 256, 0, stream>>>(W1, W2, Wt);

  // CSR build
  zero_ints_kernel<<<(N_NODES + 255) / 256, 256, 0, stream>>>(counts, N_NODES);
  hist_kernel<<<NGRP * NSLOT, 256, 0, stream>>>(erows, counts);
  scan_block_kernel<<<NSCAN, 1024, 0, stream>>>(counts, offsets, bsums, N_NODES);
  scan_sums_kernel<<<1, 128, 0, stream>>>(bsums, bbase, NSCAN, offsets);
  scan_add_kernel<<<NSCAN, 1024, 0, stream>>>(counts, offsets, bbase, cursor, N_NODES);
  bin_kernel<<<NGRP * NSLOT, 256, 0, stream>>>(erows, ecols, ev, cursor, sedge);

  // fused SpMM + GEMM -> out
  spmm_gemm_kernel<<<MPAD / 32, 256, 0, stream>>>(embB, offsets, sedge, Wt, out);

  (void)in_sizes; (void)n_in; (void)out_size; (void)ws_size;
}

// Round 7
// 766.688 us; speedup vs baseline: 1.1121x; 1.1121x over previous
//
#include <hip/hip_runtime.h>
#include <cstdint>
#include <cstddef>

#define N_NODES 100000
#define N_EDGES 3200000
#define DD 256
#define KK 512            // concatenated K: [emb+nb | nb*emb]
#define MPAD 100096       // 782 * 128
#define NSCAN 98          // ceil(N_NODES / 1024)
#define NGRP 8            // row-groups (== XCDs, heuristic)
#define GRP_ROWS 12500    // N_NODES / NGRP
#define NSLOT 256         // edge slots
#define SLOT_E 12500      // N_EDGES / NSLOT

typedef __attribute__((ext_vector_type(8))) __bf16 bf16x8;
typedef __attribute__((ext_vector_type(4))) __bf16 bf16x4;
typedef __attribute__((ext_vector_type(4))) float f32x4;

__device__ __forceinline__ void gload_lds16(const void* gsrc, void* lds) {
  __builtin_amdgcn_global_load_lds((const __attribute__((address_space(1))) void*)gsrc,
                                   (__attribute__((address_space(3))) void*)lds,
                                   16, 0, 0);
}

// ---------------- converts ----------------

__global__ void conve_kernel(const float* __restrict__ emb, __bf16* __restrict__ embB) {
  int i = blockIdx.x * blockDim.x + threadIdx.x;   // quad index, N*64 total
  float4 v = ((const float4*)emb)[i];
  bf16x4 o;
  o[0] = (__bf16)v.x; o[1] = (__bf16)v.y; o[2] = (__bf16)v.z; o[3] = (__bf16)v.w;
  ((bf16x4*)embB)[i] = o;
}

// Wt[n][k] = (k<256 ? W1[k][n] : W2[k-256][n]) as bf16, row-major [256][512]
__global__ void convw_kernel(const float* __restrict__ W1, const float* __restrict__ W2,
                             __bf16* __restrict__ Wt) {
  int idx = blockIdx.x * blockDim.x + threadIdx.x; // 0..131071 ; idx = n*512 + k
  int n = idx >> 9;
  int k = idx & 511;
  float v = (k < 256) ? W1[k * 256 + n] : W2[(k - 256) * 256 + n];
  Wt[idx] = (__bf16)v;
}

// ---------------- CSR build ----------------

__global__ void zero_ints_kernel(int* __restrict__ p, int n) {
  int i = blockIdx.x * blockDim.x + threadIdx.x;
  if (i < n) p[i] = 0;
}

// XCD-localized histogram: block b -> row-group (b&7), edge slot (b>>3).
// counts lines for group g are touched by ONE XCD -> atomics stay in local L2.
__global__ void hist_kernel(const int* __restrict__ rows, int* __restrict__ counts) {
  const int g = blockIdx.x & (NGRP - 1);
  const int s = blockIdx.x >> 3;
  const int rlo = g * GRP_ROWS;
  const int rhi = rlo + GRP_ROWS;
  const int base = s * SLOT_E;
  for (int i = base + threadIdx.x; i < base + SLOT_E; i += 256) {
    int r = rows[i];
    if (r >= rlo && r < rhi) atomicAdd(&counts[r], 1);
  }
}

__global__ void scan_block_kernel(const int* __restrict__ counts, int* __restrict__ offsets,
                                  int* __restrict__ blockSums, int n) {
  __shared__ int s[1024];
  int t = threadIdx.x;
  int i = blockIdx.x * 1024 + t;
  int v = (i < n) ? counts[i] : 0;
  s[t] = v;
  __syncthreads();
  for (int off = 1; off < 1024; off <<= 1) {
    int x = (t >= off) ? s[t - off] : 0;
    __syncthreads();
    s[t] += x;
    __syncthreads();
  }
  if (i < n) offsets[i + 1] = s[t];       // block-local inclusive scan (base added later)
  if (t == 1023) blockSums[blockIdx.x] = s[1023];
}

__global__ void scan_sums_kernel(const int* __restrict__ blockSums, int* __restrict__ blockBase,
                                 int nb, int* __restrict__ offsets) {
  __shared__ int s[128];
  int t = threadIdx.x;          // launched with 128 threads, nb <= 128
  int v = (t < nb) ? blockSums[t] : 0;
  s[t] = v;
  __syncthreads();
  for (int off = 1; off < 128; off <<= 1) {
    int x = (t >= off) ? s[t - off] : 0;
    __syncthreads();
    s[t] += x;
    __syncthreads();
  }
  if (t < nb) blockBase[t] = s[t] - v;    // exclusive
  if (t == 0) offsets[0] = 0;
}

__global__ void scan_add_kernel(const int* __restrict__ counts, int* __restrict__ offsets,
                                const int* __restrict__ blockBase, int* __restrict__ cursor, int n) {
  int i = blockIdx.x * 1024 + threadIdx.x;
  if (i < n) {
    int incl = offsets[i + 1] + blockBase[blockIdx.x];
    offsets[i + 1] = incl;
    cursor[i] = incl - counts[i];         // exclusive prefix = row start
  }
}

// XCD-localized packed binning (round-4 win: WRITE_SIZE 293MB -> ~1x)
__global__ void bin_kernel(const int* __restrict__ rows, const int* __restrict__ cols,
                           const float* __restrict__ vals, int* __restrict__ cursor,
                           uint2* __restrict__ sedge) {
  const int g = blockIdx.x & (NGRP - 1);
  const int s = blockIdx.x >> 3;
  const int rlo = g * GRP_ROWS;
  const int rhi = rlo + GRP_ROWS;
  const int base = s * SLOT_E;
  for (int i = base + threadIdx.x; i < base + SLOT_E; i += 256) {
    int r = rows[i];
    if (r >= rlo && r < rhi) {
      int pos = atomicAdd(&cursor[r], 1);
      sedge[pos] = make_uint2((unsigned)cols[i], __float_as_uint(vals[i]));
    }
  }
}

// ---------------- fused SpMM: one wave per row, unroll 8 ----------------
// X[r][0:256]   = bf16(emb[r] + nb[r])
// X[r][256:512] = bf16(emb[r] * nb[r])

__global__ void spmm_fuse_kernel(const __bf16* __restrict__ embB, const int* __restrict__ offsets,
                                 const uint2* __restrict__ sedge, __bf16* __restrict__ X) {
  int gw = (blockIdx.x << 2) + (threadIdx.x >> 6);  // 4 waves / 256-thread block
  int lane = threadIdx.x & 63;
  bf16x4* xp1 = (bf16x4*)(X + (size_t)gw * KK + 4 * lane);
  bf16x4* xp2 = (bf16x4*)(X + (size_t)gw * KK + DD + 4 * lane);
  if (gw >= N_NODES) {                              // pad rows -> zeros
    bf16x4 z;
    z[0] = (__bf16)0.f; z[1] = (__bf16)0.f; z[2] = (__bf16)0.f; z[3] = (__bf16)0.f;
    *xp1 = z; *xp2 = z;
    return;
  }
  const bf16x4* ev = (const bf16x4*)embB;           // ev[c*64 + lane] = emb[c][4l..4l+3]
  float ax = 0.f, ay = 0.f, az = 0.f, aw = 0.f;
  int e = offsets[gw];
  const int eend = offsets[gw + 1];
  // unroll x8: 8 gathers in flight
  for (; e + 7 < eend; e += 8) {
    uint2 ee[8];
    bf16x4 xx[8];
#pragma unroll
    for (int u = 0; u < 8; ++u) ee[u] = sedge[e + u];
#pragma unroll
    for (int u = 0; u < 8; ++u) xx[u] = ev[(size_t)ee[u].x * 64 + lane];
#pragma unroll
    for (int u = 0; u < 8; ++u) {
      float v = __uint_as_float(ee[u].y);
      ax = fmaf(v, (float)xx[u][0], ax); ay = fmaf(v, (float)xx[u][1], ay);
      az = fmaf(v, (float)xx[u][2], az); aw = fmaf(v, (float)xx[u][3], aw);
    }
  }
  for (; e + 3 < eend; e += 4) {
    uint2 ee[4];
    bf16x4 xx[4];
#pragma unroll
    for (int u = 0; u < 4; ++u) ee[u] = sedge[e + u];
#pragma unroll
    for (int u = 0; u < 4; ++u) xx[u] = ev[(size_t)ee[u].x * 64 + lane];
#pragma unroll
    for (int u = 0; u < 4; ++u) {
      float v = __uint_as_float(ee[u].y);
      ax = fmaf(v, (float)xx[u][0], ax); ay = fmaf(v, (float)xx[u][1], ay);
      az = fmaf(v, (float)xx[u][2], az); aw = fmaf(v, (float)xx[u][3], aw);
    }
  }
  for (; e < eend; ++e) {
    uint2 ee = sedge[e];
    float v = __uint_as_float(ee.y);
    bf16x4 x = ev[(size_t)ee.x * 64 + lane];
    ax = fmaf(v, (float)x[0], ax); ay = fmaf(v, (float)x[1], ay);
    az = fmaf(v, (float)x[2], az); aw = fmaf(v, (float)x[3], aw);
  }
  bf16x4 er = ev[(size_t)gw * 64 + lane];
  float ex = (float)er[0], ey = (float)er[1], ez = (float)er[2], ew = (float)er[3];
  bf16x4 o1, o2;
  o1[0] = (__bf16)(ex + ax); o1[1] = (__bf16)(ey + ay);
  o1[2] = (__bf16)(ez + az); o1[3] = (__bf16)(ew + aw);
  o2[0] = (__bf16)(ex * ax); o2[1] = (__bf16)(ey * ay);
  o2[2] = (__bf16)(ez * az); o2[3] = (__bf16)(ew * aw);
  *xp1 = o1;
  *xp2 = o2;
}

// ---------------- GEMM: out[M=100000, N=256] = X[M,512] @ Wt^T ----------------
// m97-style 128x128 tile, BK=64, 4 waves. T2 LDS swizzle (rule #21): linear
// global_load_lds DEST + inverse-swizzled global SOURCE (chunk = lcol^lrow)
// + XOR-swizzled ds_read (byte ^= (row&7)<<4). Row stride 128B == 32 banks,
// so un-swizzled reads were 16-way bank conflicts; swizzle spreads 8 slots.

__global__ __launch_bounds__(256) void gemm_kernel(const __bf16* __restrict__ X,
                                                   const __bf16* __restrict__ Wt,
                                                   float* __restrict__ out) {
  __shared__ __align__(16) __bf16 As[128 * 64];   // [m][k], 128B rows, swizzled content
  __shared__ __align__(16) __bf16 Bs[128 * 64];   // [n][k]
  const int t = threadIdx.x;
  const int w = t >> 6, lane = t & 63;
  const int m0 = blockIdx.x * 128;
  const int n0 = blockIdx.y * 128;
  const int wm = (w >> 1) * 64, wn = (w & 1) * 64;
  const int lrow = lane >> 3, lcol = lane & 7;    // staging: 8 rows x 8 chunks per wave-instr
  const int scol = (lcol ^ lrow) * 8;             // inverse-swizzled source k-offset

  f32x4 acc[4][4];
#pragma unroll
  for (int i = 0; i < 4; ++i)
#pragma unroll
    for (int j = 0; j < 4; ++j) {
      f32x4 z = {0.f, 0.f, 0.f, 0.f};
      acc[i][j] = z;
    }

  for (int kt = 0; kt < KK; kt += 64) {
#pragma unroll
    for (int q = 0; q < 4; ++q) {
      const int cbase = w * 256 + q * 64;         // chunk base (16B chunks), HW adds +lane*16
      const int arow = m0 + w * 32 + q * 8 + lrow;
      gload_lds16(X + (size_t)arow * KK + kt + scol, (char*)As + cbase * 16);
      const int brow = n0 + w * 32 + q * 8 + lrow;
      gload_lds16(Wt + (size_t)brow * KK + kt + scol, (char*)Bs + cbase * 16);
    }
    __syncthreads();
    const int l15 = lane & 15, lhi = lane >> 4;
#pragma unroll
    for (int kk = 0; kk < 64; kk += 32) {
      bf16x8 af[4], bg[4];
#pragma unroll
      for (int i = 0; i < 4; ++i) {
        const int ar = wm + i * 16 + l15;
        af[i] = *(const bf16x8*)((const char*)As + ar * 128 +
                                 (((kk + lhi * 8) * 2) ^ ((ar & 7) << 4)));
      }
#pragma unroll
      for (int j = 0; j < 4; ++j) {
        const int br = wn + j * 16 + l15;
        bg[j] = *(const bf16x8*)((const char*)Bs + br * 128 +
                                 (((kk + lhi * 8) * 2) ^ ((br & 7) << 4)));
      }
#pragma unroll
      for (int i = 0; i < 4; ++i)
#pragma unroll
        for (int j = 0; j < 4; ++j)
          acc[i][j] = __builtin_amdgcn_mfma_f32_16x16x32_bf16(af[i], bg[j], acc[i][j], 0, 0, 0);
    }
    __syncthreads();
  }

  const int orow0 = m0 + wm + ((lane >> 4) << 2);
  const int ocol0 = n0 + wn + (lane & 15);
#pragma unroll
  for (int i = 0; i < 4; ++i)
#pragma unroll
    for (int j = 0; j < 4; ++j)
#pragma unroll
      for (int r = 0; r < 4; ++r) {
        const int row = orow0 + i * 16 + r;
        if (row < N_NODES) out[(size_t)row * DD + ocol0 + j * 16] = acc[i][j][r];
      }
}

// ---------------- launch ----------------

extern "C" void kernel_launch(void* const* d_in, const int* in_sizes, int n_in,
                              void* d_out, int out_size, void* d_ws, size_t ws_size,
                              hipStream_t stream) {
  const float* emb  = (const float*)d_in[0];
  const float* ev   = (const float*)d_in[1];
  const float* W1   = (const float*)d_in[2];
  const float* W2   = (const float*)d_in[3];
  const int* erows  = (const int*)d_in[4];
  const int* ecols  = (const int*)d_in[5];
  float* out = (float*)d_out;
  char* ws = (char*)d_ws;

  // workspace layout (proven 181MB footprint from round 4)
  const size_t OFF_X   = 0;                                    // MPAD*512*2   = 102,498,304
  const size_t OFF_EMB = OFF_X   + (size_t)MPAD * KK * 2;      // N*256*2     = 51,200,000
  const size_t OFF_WT  = OFF_EMB + (size_t)N_NODES * DD * 2;   // 512*256*2   = 262,144
  const size_t OFF_CNT = OFF_WT  + (size_t)KK * DD * 2;
  const size_t OFF_OFS = OFF_CNT + 401408;
  const size_t OFF_CUR = OFF_OFS + 401408;
  const size_t OFF_BS  = OFF_CUR + 401408;
  const size_t OFF_BB  = OFF_BS  + 4096;
  const size_t OFF_SE  = OFF_BB  + 4096;                       // N_EDGES*8 packed (col,val)

  __bf16* X     = (__bf16*)(ws + OFF_X);
  __bf16* embB  = (__bf16*)(ws + OFF_EMB);
  __bf16* Wt    = (__bf16*)(ws + OFF_WT);
  int* counts   = (int*)(ws + OFF_CNT);
  int* offsets  = (int*)(ws + OFF_OFS);
  int* cursor   = (int*)(ws + OFF_CUR);
  int* bsums    = (int*)(ws + OFF_BS);
  int* bbase    = (int*)(ws + OFF_BB);
  uint2* sedge  = (uint2*)(ws + OFF_SE);

  // converts (independent)
  conve_kernel<<<(N_NODES * 64) / 256, 256, 0, stream>>>(emb, embB);
  convw_kernel<<<(KK * DD) / 256, 256, 0, stream>>>(W1, W2, Wt);

  // CSR build
  zero_ints_kernel<<<(N_NODES + 255) / 256, 256, 0, stream>>>(counts, N_NODES);
  hist_kernel<<<NGRP * NSLOT, 256, 0, stream>>>(erows, counts);
  scan_block_kernel<<<NSCAN, 1024, 0, stream>>>(counts, offsets, bsums, N_NODES);
  scan_sums_kernel<<<1, 128, 0, stream>>>(bsums, bbase, NSCAN, offsets);
  scan_add_kernel<<<NSCAN, 1024, 0, stream>>>(counts, offsets, bbase, cursor, N_NODES);
  bin_kernel<<<NGRP * NSLOT, 256, 0, stream>>>(erows, ecols, ev, cursor, sedge);

  // fused SpMM -> X = [emb+nb | nb*emb] (bf16)
  spmm_fuse_kernel<<<MPAD / 4, 256, 0, stream>>>(embB, offsets, sedge, X);

  // single K=512 MFMA GEMM -> out
  gemm_kernel<<<dim3(MPAD / 128, 2), 256, 0, stream>>>(X, Wt, out);

  (void)in_sizes; (void)n_in; (void)out_size; (void)ws_size;
}